// Round 2
// baseline (616.111 us; speedup 1.0000x reference)
//
#include <hip/hip_runtime.h>
#include <hip/hip_bf16.h>
#include <math.h>

// ---------------------------------------------------------------------------
// FederatedPPOAgent: 3x GCNConv (N=100k, E=3.2M, D=128) + actor/critic MLPs.
//
// R11 changes vs R10:
//  - agg_gemm_k: __launch_bounds__(256,8) -> (256,4). R10's 8-waves/EU pin
//    capped the unified VGPR/AGPR budget at 64 and the compiler spilled the
//    aggregation loop to scratch: WRITE_SIZE 220MB (vs ~13MB ideal), FETCH
//    +105MB, 182us vs agg128's 67us. Grid-stride needs no co-residency, so
//    the pin bought nothing. Cap 128 eliminates scratch; predicted ~85us.
//  - everything else unchanged from R10 (fused agg+gemm, fused heads).
// ---------------------------------------------------------------------------

#define WS_ALIGN(x) (((x) + 255) & ~(size_t)255)

constexpr int RNG  = 64;        // node ranges
constexpr int NRG  = 1563;      // nodes per range (64*1563 >= 100000)
constexpr int NB   = 1024;      // bucket-phase blocks
constexpr int CHK  = 16;        // per-range fill chunks

constexpr float S_FP8     = 64.0f;
constexpr float S_FP8_INV = 1.0f / 64.0f;

using bf16x8 = __attribute__((ext_vector_type(8))) short;
using f32x4  = __attribute__((ext_vector_type(4))) float;
using f32x2  = __attribute__((ext_vector_type(2))) float;

__device__ __forceinline__ float b2f(unsigned short u) {
    return __uint_as_float(((unsigned int)u) << 16);
}
__device__ __forceinline__ unsigned short f2b(float f) {
    __hip_bfloat16 hb = __float2bfloat16(f);
    return *(unsigned short*)&hb;
}
__device__ __forceinline__ unsigned char f2fp8(float f) {
    return (unsigned char)(__builtin_amdgcn_cvt_pk_fp8_f32(f, f, 0, false) & 0xff);
}
__device__ __forceinline__ int pad8(int v) { return (v + 7) & ~7; }

// 8 fp8 (uint2) -> 4 packed-f32 accumulators
__device__ __forceinline__ void acc8(uint2 u, f32x2& a01, f32x2& a23,
                                     f32x2& a45, f32x2& a67) {
    a01 += __builtin_amdgcn_cvt_pk_f32_fp8((int)u.x, false);
    a23 += __builtin_amdgcn_cvt_pk_f32_fp8((int)u.x, true);
    a45 += __builtin_amdgcn_cvt_pk_f32_fp8((int)u.y, false);
    a67 += __builtin_amdgcn_cvt_pk_f32_fp8((int)u.y, true);
}

// ---------------- CSR build ----------------

__global__ __launch_bounds__(256) void bucket_count_k(
    const int* __restrict__ dst, int* __restrict__ bcnt, int E) {
    __shared__ int c64[RNG];
    int b = blockIdx.x, t = threadIdx.x;
    if (t < RNG) c64[t] = 0;
    __syncthreads();
    int ec = (E + NB - 1) / NB;
    int e0 = b * ec, e1 = min(E, e0 + ec);
    for (int e = e0 + t; e < e1; e += 256) {
        int d = __builtin_nontemporal_load(dst + e);
        atomicAdd(&c64[d / NRG], 1);
    }
    __syncthreads();
    if (t < RNG) bcnt[t * NB + b] = c64[t];
}

// block r: exclusive scan of bcnt[r][0..NB) -> base, total -> rtot[r]
__global__ __launch_bounds__(256) void rsum_k(
    const int* __restrict__ bcnt, int* __restrict__ base, int* __restrict__ rtot) {
    __shared__ int s[256];
    int r = blockIdx.x, t = threadIdx.x;
    const int* row = bcnt + (size_t)r * NB;
    int v[4], loc = 0;
#pragma unroll
    for (int j = 0; j < 4; j++) { v[j] = row[t * 4 + j]; loc += v[j]; }
    s[t] = loc;
    __syncthreads();
    for (int d = 1; d < 256; d <<= 1) {
        int x = (t >= d) ? s[t - d] : 0;
        __syncthreads();
        s[t] += x;
        __syncthreads();
    }
    int run = s[t] - loc;   // exclusive
    int* bp = base + (size_t)r * NB + t * 4;
#pragma unroll
    for (int j = 0; j < 4; j++) { bp[j] = run; run += v[j]; }
    if (t == 255) rtot[r] = s[255];
}

__global__ void rstart_k(const int* __restrict__ rtot, int* __restrict__ bstart, int E) {
    if (threadIdx.x == 0) {
        int run = 0;
        for (int r = 0; r < RNG; r++) { bstart[r] = run; run += rtot[r]; }
        bstart[RNG] = run;
    }
}

__global__ __launch_bounds__(256) void bucket_scatter_k(
    const int* __restrict__ src, const int* __restrict__ dst,
    const int* __restrict__ base, const int* __restrict__ bstart,
    unsigned* __restrict__ bucket, int E) {
    __shared__ int cur[RNG];
    int b = blockIdx.x, t = threadIdx.x;
    if (t < RNG) cur[t] = bstart[t] + base[(size_t)t * NB + b];
    __syncthreads();
    int ec = (E + NB - 1) / NB;
    int e0 = b * ec, e1 = min(E, e0 + ec);
    for (int e = e0 + t; e < e1; e += 256) {
        int d = __builtin_nontemporal_load(dst + e);
        int sv = __builtin_nontemporal_load(src + e);
        int r = d / NRG;
        int pos = atomicAdd(&cur[r], 1);
        bucket[pos] = ((unsigned)(d - r * NRG) << 17) | (unsigned)sv;
    }
}

__global__ __launch_bounds__(256) void hist_bucket_k(
    const unsigned* __restrict__ bucket, const int* __restrict__ bstart,
    int* __restrict__ hist) {
    __shared__ int h[NRG];
    int b = blockIdx.x, r = b & 63, c2 = b >> 6, t = threadIdx.x;
    for (int i = t; i < NRG; i += 256) h[i] = 0;
    int s0 = bstart[r], s1 = bstart[r + 1];
    int ec = (s1 - s0 + CHK - 1) / CHK;
    int e0 = s0 + c2 * ec, e1 = min(s1, e0 + ec);
    __syncthreads();
    for (int e = e0 + t; e < e1; e += 256) {
        unsigned v = __builtin_nontemporal_load(bucket + e);
        atomicAdd(&h[v >> 17], 1);
    }
    __syncthreads();
    int* out = hist + ((size_t)r * CHK + c2) * NRG;
    for (int i = t; i < NRG; i += 256) out[i] = h[i];
}

__global__ void sum_hist_dinv_k(const int* __restrict__ hist, int* __restrict__ cnt,
                                float* __restrict__ dinv, int N) {
    int i = blockIdx.x * 256 + threadIdx.x;
    if (i >= N) return;
    int r = i / NRG, li = i - r * NRG;
    const int* hp = hist + ((size_t)r * CHK) * NRG + li;
    int s = 0;
#pragma unroll
    for (int c = 0; c < CHK; c++) s += hp[(size_t)c * NRG];
    cnt[i] = s;
    dinv[i] = rsqrtf((float)s + 1.0f);   // +1: self loop
}

// prefix sums over PADDED counts (pad8)
__global__ void chunk_sum_k(const int* __restrict__ cnt, int* __restrict__ bsum, int n) {
    __shared__ int sd[256];
    int t = threadIdx.x;
    int i = blockIdx.x * 256 + t;
    sd[t] = (i < n) ? pad8(cnt[i]) : 0;
    __syncthreads();
    for (int d = 128; d > 0; d >>= 1) {
        if (t < d) sd[t] += sd[t + d];
        __syncthreads();
    }
    if (t == 0) bsum[blockIdx.x] = sd[0];
}

__global__ void scan_mid_k(const int* __restrict__ bsum, int* __restrict__ boff,
                           int nb, int* __restrict__ rowptr, int N) {
    __shared__ int s[512];
    int t = threadIdx.x;
    s[t] = (t < nb) ? bsum[t] : 0;
    __syncthreads();
    if (t == 0) {
        int run = 0;
        for (int i = 0; i < nb; i++) { int v = s[i]; s[i] = run; run += v; }
        rowptr[N] = run;
    }
    __syncthreads();
    if (t < nb) boff[t] = s[t];
}

// scan_final + offsets + pad_col fused
__global__ void scan_off_pad_k(const int* __restrict__ cnt, const int* __restrict__ boff,
                               int* __restrict__ rowptr, int* __restrict__ hist,
                               int* __restrict__ col, int N) {
    __shared__ int s[256];
    int t = threadIdx.x;
    int i = blockIdx.x * 256 + t;
    int cv = (i < N) ? cnt[i] : 0;
    int v = pad8(cv);
    if (i >= N) v = 0;
    s[t] = v;
    __syncthreads();
    for (int d = 1; d < 256; d <<= 1) {
        int x = (t >= d) ? s[t - d] : 0;
        __syncthreads();
        s[t] += x;
        __syncthreads();
    }
    if (i < N) {
        int rp = s[t] - v + boff[blockIdx.x];
        rowptr[i] = rp;
        // offsets: hist[r][c][li] -> running cursor
        int r = i / NRG, li = i - r * NRG;
        int* hp = hist + ((size_t)r * CHK) * NRG + li;
        int run = rp;
#pragma unroll
        for (int c = 0; c < CHK; c++) {
            int hv = hp[(size_t)c * NRG];
            hp[(size_t)c * NRG] = run;
            run += hv;
        }
        // pad slots -> zero-row N
        for (int e = rp + cv; e < rp + v; e++) col[e] = N;
    }
}

__global__ __launch_bounds__(256) void fill2_k(
    const unsigned* __restrict__ bucket, const int* __restrict__ bstart,
    const int* __restrict__ hist, int* __restrict__ col) {
    __shared__ int cur[NRG];
    int b = blockIdx.x, r = b & 63, c2 = b >> 6, t = threadIdx.x;
    const int* hp = hist + ((size_t)r * CHK + c2) * NRG;
    for (int i = t; i < NRG; i += 256) cur[i] = hp[i];
    int s0 = bstart[r], s1 = bstart[r + 1];
    int ec = (s1 - s0 + CHK - 1) / CHK;
    int e0 = s0 + c2 * ec, e1 = min(s1, e0 + ec);
    __syncthreads();
    for (int e = e0 + t; e < e1; e += 256) {
        unsigned v = __builtin_nontemporal_load(bucket + e);
        int slot = atomicAdd(&cur[v >> 17], 1);   // LDS atomic
        col[slot] = (int)(v & 0x1FFFFu);
    }
}

// ---------------- weight prep: fp32 W[K][OUT] -> bf16 W^T[OUT][K] ----------------
// Layout: W1t(16384) W2t(16384) W3t(8192) Wh1t(16384: Wa1 rows 0..127,
// Wc1 rows 128..255, K=64) Wa2t(8192) Wc2t(8192)

__global__ __launch_bounds__(256) void prep_w_k(
    const float* __restrict__ W1, const float* __restrict__ W2,
    const float* __restrict__ W3, const float* __restrict__ Wa1,
    const float* __restrict__ Wc1, const float* __restrict__ Wa2,
    const float* __restrict__ Wc2, unsigned short* __restrict__ wt) {
    int i = blockIdx.x * 256 + threadIdx.x;   // 0..73727
    const float* W; int off, K, OUT;
    if (i < 16384)      { W = W1;  off = 0;     K = 128; OUT = 128; }
    else if (i < 32768) { W = W2;  off = 16384; K = 128; OUT = 128; }
    else if (i < 40960) { W = W3;  off = 32768; K = 128; OUT = 64; }
    else if (i < 49152) { W = Wa1; off = 40960; K = 64;  OUT = 128; }
    else if (i < 57344) { W = Wc1; off = 49152; K = 64;  OUT = 128; }
    else if (i < 65536) { W = Wa2; off = 57344; K = 128; OUT = 64; }
    else                { W = Wc2; off = 65536; K = 128; OUT = 64; }
    int j = i - off, k = j / OUT, n = j - k * OUT;
    wt[off + n * K + k] = f2b(W[j]);
}

// ---------------- gemm2: weights-stationary grid-stride MFMA GEMM ----------------
// (only EPI 0 instantiated: fp8(acc * dinv[row] * S), zero pad rows)

template <int K, int OUT, int EPI, bool AF32>
__global__ __launch_bounds__(256) void gemm2_k(
    const void* __restrict__ Xv, int ldx, const unsigned short* __restrict__ Wt,
    const float* __restrict__ sb, const float* __restrict__ w3b,
    const float* __restrict__ b3, void* __restrict__ Yv, int N, int NT) {
    constexpr int LDK = K + 8;
    __shared__ __align__(16) unsigned short Bs[OUT * LDK];
    __shared__ __align__(16) unsigned short As[64 * LDK];
    int t = threadIdx.x;

    // stage B once per block (visible after first in-loop barrier)
    for (int g = t; g < OUT * (K / 8); g += 256) {
        int r = g / (K / 8), q = g - r * (K / 8);
        *(uint4*)&Bs[r * LDK + q * 8] = *(const uint4*)(Wt + r * K + q * 8);
    }

    int wv = t >> 6, lane = t & 63;
    int lm = lane & 15, lq = lane >> 4;
    constexpr int CT = OUT / 16;

    for (int tile = blockIdx.x; tile < NT; tile += gridDim.x) {
        int rowBase = tile * 64;

        // stage A tile
        if constexpr (AF32) {
            const float* X = (const float*)Xv;
            for (int g = t; g < 64 * (K / 8); g += 256) {
                int r = g / (K / 8), q = g - r * (K / 8);
                int gr = rowBase + r;
                unsigned short us[8];
                if (gr < N) {
                    float4 v0 = *(const float4*)(X + (size_t)gr * ldx + q * 8);
                    float4 v1 = *(const float4*)(X + (size_t)gr * ldx + q * 8 + 4);
                    us[0] = f2b(v0.x); us[1] = f2b(v0.y); us[2] = f2b(v0.z); us[3] = f2b(v0.w);
                    us[4] = f2b(v1.x); us[5] = f2b(v1.y); us[6] = f2b(v1.z); us[7] = f2b(v1.w);
                } else {
#pragma unroll
                    for (int j = 0; j < 8; j++) us[j] = 0;
                }
                *(uint4*)&As[r * LDK + q * 8] = *(uint4*)us;
            }
        } else {
            const unsigned short* X = (const unsigned short*)Xv;
            for (int g = t; g < 64 * (K / 8); g += 256) {
                int r = g / (K / 8), q = g - r * (K / 8);
                int gr = rowBase + r;
                uint4 v = make_uint4(0, 0, 0, 0);
                if (gr < N) v = *(const uint4*)(X + (size_t)gr * ldx + q * 8);
                *(uint4*)&As[r * LDK + q * 8] = v;
            }
        }
        __syncthreads();

        f32x4 acc[CT];
#pragma unroll
        for (int c = 0; c < CT; c++) acc[c] = (f32x4){0.f, 0.f, 0.f, 0.f};

        const unsigned short* arow = &As[(wv * 16 + lm) * LDK + lq * 8];
#pragma unroll
        for (int kt = 0; kt < K / 32; kt++) {
            bf16x8 a = *(const bf16x8*)(arow + kt * 32);
#pragma unroll
            for (int c = 0; c < CT; c++) {
                bf16x8 b = *(const bf16x8*)&Bs[(c * 16 + lm) * LDK + kt * 32 + lq * 8];
                acc[c] = __builtin_amdgcn_mfma_f32_16x16x32_bf16(a, b, acc[c], 0, 0, 0);
            }
        }

        // epilogue: C/D layout col=lane&15, row=(lane>>4)*4+reg [m89/m91]
        int r0 = rowBase + wv * 16 + lq * 4;
        if constexpr (EPI == 0) {
#pragma unroll
            for (int r = 0; r < 4; r++) {
                int gr = r0 + r;
                float scale = (gr < N) ? sb[gr] * S_FP8 : 0.f;
#pragma unroll
                for (int c = 0; c < CT; c++) {
                    int colg = c * 16 + lm;
                    ((unsigned char*)Yv)[(size_t)gr * OUT + colg] = f2fp8(acc[c][r] * scale);
                }
            }
        }
        __syncthreads();   // protect As before next tile's staging
    }
}

// ---------------- fused aggregation + weight GEMM ----------------
// Per-wave 16-row tiles, no barriers. Wave aggregates 16 nodes (gather fp8
// neighbors + self, *dinv, +bias, relu -> bf16 row in wave-private LDS),
// then MFMA x Wt[OUT][128] (B-frags from global, W is L1/L2 resident),
// EPI0 fp8 write with dinv[row]*S pre-scale.
// launch_bounds(256,4): VGPR cap 128 -> no scratch spill (R10's (256,8)
// cap-64 spilled ~50KB/wave-tile: WRITE 220MB, FETCH +105MB, 182us).

template <int OUT>
__global__ __launch_bounds__(256, 4) void agg_gemm_k(
    const unsigned char* __restrict__ H,   // [Npad+64,128] fp8, rows>=N zero
    const int* __restrict__ rowptr, const int* __restrict__ col,
    const float* __restrict__ dinv, const float* __restrict__ bias,
    const unsigned short* __restrict__ Wt,  // [OUT][128] bf16
    unsigned char* __restrict__ Y,          // [Npad+64,OUT] fp8
    int N, int Ecap, int NT16) {
    constexpr int K = 128, LDK = K + 8;
    __shared__ __align__(16) unsigned short As[4 * 16 * LDK];
    int t = threadIdx.x, wv = t >> 6, lane = t & 63;
    unsigned short* Aw = &As[wv * 16 * LDK];
    int lm = lane & 15, lq = lane >> 4;
    int grp = lq, li8 = lm * 8;
    int stride = gridDim.x << 2;

    for (int tile = blockIdx.x * 4 + wv; tile < NT16; tile += stride) {
        int base = tile * 16;

        // ---- phase 1: aggregate 16 nodes into wave-private LDS rows ----
        for (int i = 0; i < 16; i++) {
            int node = base + i;
            if (node < N) {
                f32x2 a01 = {0.f, 0.f}, a23 = {0.f, 0.f}, a45 = {0.f, 0.f}, a67 = {0.f, 0.f};
                if (grp == 0) {
                    uint2 u = *(const uint2*)(H + (size_t)node * 128 + li8);
                    acc8(u, a01, a23, a45, a67);
                }
                int start = rowptr[node], end = rowptr[node + 1];
                for (int e0 = start; e0 < end; e0 += 64) {
                    int cv = col[min(e0 + lane, Ecap - 1)];
                    int quads = min(64, end - e0) >> 2;
                    for (int q = 0; q < quads; q += 2) {
                        int s0 = __shfl(cv, 4 * q + grp, 64);
                        int s1 = __shfl(cv, 4 * q + 4 + grp, 64);
                        uint2 u0 = *(const uint2*)(H + (size_t)s0 * 128 + li8);
                        uint2 u1 = *(const uint2*)(H + (size_t)s1 * 128 + li8);
                        acc8(u0, a01, a23, a45, a67);
                        acc8(u1, a01, a23, a45, a67);
                    }
                }
#pragma unroll
                for (int w = 16; w < 64; w <<= 1) {
                    a01[0] += __shfl_xor(a01[0], w, 64); a01[1] += __shfl_xor(a01[1], w, 64);
                    a23[0] += __shfl_xor(a23[0], w, 64); a23[1] += __shfl_xor(a23[1], w, 64);
                    a45[0] += __shfl_xor(a45[0], w, 64); a45[1] += __shfl_xor(a45[1], w, 64);
                    a67[0] += __shfl_xor(a67[0], w, 64); a67[1] += __shfl_xor(a67[1], w, 64);
                }
                if (grp == 0) {
                    float dv = dinv[node] * S_FP8_INV;
                    float4 b0 = *(const float4*)(bias + li8);
                    float4 b1 = *(const float4*)(bias + li8 + 4);
                    float o0 = fmaxf(a01[0] * dv + b0.x, 0.f), o1 = fmaxf(a01[1] * dv + b0.y, 0.f);
                    float o2 = fmaxf(a23[0] * dv + b0.z, 0.f), o3 = fmaxf(a23[1] * dv + b0.w, 0.f);
                    float o4 = fmaxf(a45[0] * dv + b1.x, 0.f), o5 = fmaxf(a45[1] * dv + b1.y, 0.f);
                    float o6 = fmaxf(a67[0] * dv + b1.z, 0.f), o7 = fmaxf(a67[1] * dv + b1.w, 0.f);
                    unsigned short us[8] = {f2b(o0), f2b(o1), f2b(o2), f2b(o3),
                                            f2b(o4), f2b(o5), f2b(o6), f2b(o7)};
                    *(uint4*)&Aw[i * LDK + li8] = *(uint4*)us;
                }
            } else if (grp == 0) {
                uint4 z = make_uint4(0, 0, 0, 0);
                *(uint4*)&Aw[i * LDK + li8] = z;
            }
        }

        // ---- phase 2: wave-local 16xOUT MFMA + fp8 EPI0 ----
        const unsigned short* arow = &Aw[lm * LDK + lq * 8];
#pragma unroll
        for (int c0 = 0; c0 < OUT / 16; c0 += 4) {
            f32x4 acc[4];
#pragma unroll
            for (int c = 0; c < 4; c++) acc[c] = (f32x4){0.f, 0.f, 0.f, 0.f};
#pragma unroll
            for (int kt = 0; kt < 4; kt++) {
                bf16x8 a = *(const bf16x8*)(arow + kt * 32);
#pragma unroll
                for (int c = 0; c < 4; c++) {
                    bf16x8 b = *(const bf16x8*)(Wt + (size_t)((c0 + c) * 16 + lm) * K + kt * 32 + lq * 8);
                    acc[c] = __builtin_amdgcn_mfma_f32_16x16x32_bf16(a, b, acc[c], 0, 0, 0);
                }
            }
            int r0 = base + lq * 4;
#pragma unroll
            for (int r = 0; r < 4; r++) {
                int gr = r0 + r;
                float scale = (gr < N) ? dinv[gr] * S_FP8 : 0.f;
#pragma unroll
                for (int c = 0; c < 4; c++) {
                    int colg = (c0 + c) * 16 + lm;
                    Y[(size_t)gr * OUT + colg] = f2fp8(acc[c][r] * scale);
                }
            }
        }
    }
}

// ---------------- fused actor/critic heads ----------------
// EPI 2: actor  (L1 relu -> L2 relu -> logits -> softmax -> out[0..8))
// EPI 3: critic (L1 relu -> L2 relu -> value -> out[8])
// Weights staged once per block; per 64-row tile each wave handles its own
// 16 rows end-to-end through wave-private LDS (no per-tile barriers).

template <int EPI>
__global__ __launch_bounds__(256) void heads_k(
    const unsigned short* __restrict__ h3,   // [N,64] bf16
    const unsigned short* __restrict__ W1t,  // [128][64] bf16 (head L1)
    const float* __restrict__ b1v,           // [128]
    const unsigned short* __restrict__ W2t,  // [64][128] bf16 (head L2)
    const float* __restrict__ b2v,           // [64]
    const float* __restrict__ w3,            // Wa3 [64][8] / Wc3 [64][1] fp32
    const float* __restrict__ b3v,
    float* __restrict__ out, int N, int NT) {
    constexpr int LD64 = 72, LD128 = 136;
    __shared__ __align__(16) unsigned short Bs1[128 * LD64];   // 18.4KB
    __shared__ __align__(16) unsigned short Bs2[64 * LD128];   // 17.4KB
    __shared__ __align__(16) unsigned short As[4 * 16 * LD64]; //  9.2KB
    __shared__ __align__(16) unsigned short A1[4 * 16 * LD128];// 17.4KB
    int t = threadIdx.x, wv = t >> 6, lane = t & 63;
    int lm = lane & 15, lq = lane >> 4;

    // stage head weights once per block
    for (int g = t; g < 128 * 8; g += 256) {
        int r = g >> 3, q = g & 7;
        *(uint4*)&Bs1[r * LD64 + q * 8] = *(const uint4*)(W1t + r * 64 + q * 8);
    }
    for (int g = t; g < 64 * 16; g += 256) {
        int r = g >> 4, q = g & 15;
        *(uint4*)&Bs2[r * LD128 + q * 8] = *(const uint4*)(W2t + r * 128 + q * 8);
    }
    __syncthreads();

    unsigned short* Asw = &As[wv * 16 * LD64];
    unsigned short* A1w = &A1[wv * 16 * LD128];

    for (int tile = blockIdx.x; tile < NT; tile += gridDim.x) {
        int rowBase = tile * 64 + wv * 16;

        // stage wave's 16 h3 rows
        for (int g = lane; g < 16 * 8; g += 64) {
            int r = g >> 3, q = g & 7;
            int gr = rowBase + r;
            uint4 v = make_uint4(0, 0, 0, 0);
            if (gr < N) v = *(const uint4*)(h3 + (size_t)gr * 64 + q * 8);
            *(uint4*)&Asw[r * LD64 + q * 8] = v;
        }

        // L1: 16x128, K=64
        f32x4 acc1[8];
#pragma unroll
        for (int c = 0; c < 8; c++) acc1[c] = (f32x4){0.f, 0.f, 0.f, 0.f};
        const unsigned short* arow = &Asw[lm * LD64 + lq * 8];
#pragma unroll
        for (int kt = 0; kt < 2; kt++) {
            bf16x8 a = *(const bf16x8*)(arow + kt * 32);
#pragma unroll
            for (int c = 0; c < 8; c++) {
                bf16x8 b = *(const bf16x8*)&Bs1[(c * 16 + lm) * LD64 + kt * 32 + lq * 8];
                acc1[c] = __builtin_amdgcn_mfma_f32_16x16x32_bf16(a, b, acc1[c], 0, 0, 0);
            }
        }
        // relu + bf16 -> wave-private A1
#pragma unroll
        for (int r = 0; r < 4; r++) {
            int lr = lq * 4 + r;
#pragma unroll
            for (int c = 0; c < 8; c++) {
                int colg = c * 16 + lm;
                float v = fmaxf(acc1[c][r] + b1v[colg], 0.f);
                A1w[lr * LD128 + colg] = f2b(v);
            }
        }

        // L2: 16x64, K=128
        f32x4 acc[4];
#pragma unroll
        for (int c = 0; c < 4; c++) acc[c] = (f32x4){0.f, 0.f, 0.f, 0.f};
        const unsigned short* arow2 = &A1w[lm * LD128 + lq * 8];
#pragma unroll
        for (int kt = 0; kt < 4; kt++) {
            bf16x8 a = *(const bf16x8*)(arow2 + kt * 32);
#pragma unroll
            for (int c = 0; c < 4; c++) {
                bf16x8 b = *(const bf16x8*)&Bs2[(c * 16 + lm) * LD128 + kt * 32 + lq * 8];
                acc[c] = __builtin_amdgcn_mfma_f32_16x16x32_bf16(a, b, acc[c], 0, 0, 0);
            }
        }

        int r0 = rowBase + lq * 4;
        if constexpr (EPI == 2) {
            float l[4][8];
#pragma unroll
            for (int r = 0; r < 4; r++)
#pragma unroll
                for (int a = 0; a < 8; a++) l[r][a] = 0.f;
#pragma unroll
            for (int c = 0; c < 4; c++) {
                int colg = c * 16 + lm;
#pragma unroll
                for (int r = 0; r < 4; r++) {
                    float v = fmaxf(acc[c][r] + b2v[colg], 0.f);
#pragma unroll
                    for (int a = 0; a < 8; a++)
                        l[r][a] = fmaf(v, w3[colg * 8 + a], l[r][a]);
                }
            }
#pragma unroll
            for (int w = 1; w < 16; w <<= 1)
#pragma unroll
                for (int r = 0; r < 4; r++)
#pragma unroll
                    for (int a = 0; a < 8; a++)
                        l[r][a] += __shfl_xor(l[r][a], w, 64);
            if (lm < 8) {
#pragma unroll
                for (int r = 0; r < 4; r++) {
                    int gr = r0 + r;
                    if (gr < N) {
                        float lg[8], m = -1e30f;
#pragma unroll
                        for (int a = 0; a < 8; a++) { lg[a] = l[r][a] + b3v[a]; m = fmaxf(m, lg[a]); }
                        float sum = 0.f;
#pragma unroll
                        for (int a = 0; a < 8; a++) { lg[a] = expf(lg[a] - m); sum += lg[a]; }
                        out[(size_t)gr * 9 + lm] = lg[lm] / sum;
                    }
                }
            }
        } else {   // EPI == 3: critic value
            float lv[4] = {0.f, 0.f, 0.f, 0.f};
#pragma unroll
            for (int c = 0; c < 4; c++) {
                int colg = c * 16 + lm;
#pragma unroll
                for (int r = 0; r < 4; r++) {
                    float v = fmaxf(acc[c][r] + b2v[colg], 0.f);
                    lv[r] = fmaf(v, w3[colg], lv[r]);
                }
            }
#pragma unroll
            for (int w = 1; w < 16; w <<= 1)
#pragma unroll
                for (int r = 0; r < 4; r++) lv[r] += __shfl_xor(lv[r], w, 64);
            if (lm == 0) {
#pragma unroll
                for (int r = 0; r < 4; r++) {
                    int gr = r0 + r;
                    if (gr < N) out[(size_t)gr * 9 + 8] = lv[r] + b3v[0];
                }
            }
        }
    }
}

// ---------------- final 64-ch aggregation (unchanged) ----------------

__global__ __launch_bounds__(256) void agg64_k(
    const unsigned char* __restrict__ H,   // [(Npad+64),64] fp8, rows>=N zero
    const int* __restrict__ rowptr, const int* __restrict__ col,
    const float* __restrict__ dinv, const float* __restrict__ bias,
    unsigned short* __restrict__ Y, int N, int Ecap) {
    int tid = threadIdx.x;
    int node = blockIdx.x * 4 + (tid >> 6);
    if (node >= N) return;
    int lane = tid & 63;
    int grp = lane >> 3;
    int li8 = (lane & 7) * 8;

    f32x2 a01 = {0.f, 0.f}, a23 = {0.f, 0.f}, a45 = {0.f, 0.f}, a67 = {0.f, 0.f};
    if (grp == 0) {
        uint2 u = *(const uint2*)(H + (size_t)node * 64 + li8);
        acc8(u, a01, a23, a45, a67);
    }

    int start = rowptr[node], end = rowptr[node + 1];
    for (int e0 = start; e0 < end; e0 += 64) {
        int cv = col[min(e0 + lane, Ecap - 1)];
        int octs = min(64, end - e0) >> 3;
        int o = 0;
        for (; o + 2 <= octs; o += 2) {
            int s0 = __shfl(cv, 8 * o + grp, 64);
            int s1 = __shfl(cv, 8 * o + 8 + grp, 64);
            uint2 u0 = *(const uint2*)(H + (size_t)s0 * 64 + li8);
            uint2 u1 = *(const uint2*)(H + (size_t)s1 * 64 + li8);
            acc8(u0, a01, a23, a45, a67);
            acc8(u1, a01, a23, a45, a67);
        }
        if (o < octs) {
            int s0 = __shfl(cv, 8 * o + grp, 64);
            uint2 u0 = *(const uint2*)(H + (size_t)s0 * 64 + li8);
            acc8(u0, a01, a23, a45, a67);
        }
    }

#pragma unroll
    for (int w = 8; w < 64; w <<= 1) {
        a01[0] += __shfl_xor(a01[0], w, 64); a01[1] += __shfl_xor(a01[1], w, 64);
        a23[0] += __shfl_xor(a23[0], w, 64); a23[1] += __shfl_xor(a23[1], w, 64);
        a45[0] += __shfl_xor(a45[0], w, 64); a45[1] += __shfl_xor(a45[1], w, 64);
        a67[0] += __shfl_xor(a67[0], w, 64); a67[1] += __shfl_xor(a67[1], w, 64);
    }

    if (grp == 0) {
        float dv = dinv[node] * S_FP8_INV;
        float4 b0 = *(const float4*)(bias + li8);
        float4 b1 = *(const float4*)(bias + li8 + 4);
        unsigned short us[8] = {
            f2b(a01[0] * dv + b0.x), f2b(a01[1] * dv + b0.y),
            f2b(a23[0] * dv + b0.z), f2b(a23[1] * dv + b0.w),
            f2b(a45[0] * dv + b1.x), f2b(a45[1] * dv + b1.y),
            f2b(a67[0] * dv + b1.z), f2b(a67[1] * dv + b1.w)};
        *(uint4*)(Y + (size_t)node * 64 + li8) = *(uint4*)us;
    }
}

// ---------------- launch ----------------

extern "C" void kernel_launch(void* const* d_in, const int* in_sizes, int n_in,
                              void* d_out, int out_size, void* d_ws, size_t ws_size,
                              hipStream_t stream) {
    const float* x   = (const float*)d_in[0];
    const int*   ei  = (const int*)d_in[1];
    const float* W1  = (const float*)d_in[2];  const float* b1  = (const float*)d_in[3];
    const float* W2  = (const float*)d_in[4];  const float* b2  = (const float*)d_in[5];
    const float* W3  = (const float*)d_in[6];  const float* b3  = (const float*)d_in[7];
    const float* Wa1 = (const float*)d_in[8];  const float* ba1 = (const float*)d_in[9];
    const float* Wa2 = (const float*)d_in[10]; const float* ba2 = (const float*)d_in[11];
    const float* Wa3 = (const float*)d_in[12]; const float* ba3 = (const float*)d_in[13];
    const float* Wc1 = (const float*)d_in[14]; const float* bc1 = (const float*)d_in[15];
    const float* Wc2 = (const float*)d_in[16]; const float* bc2 = (const float*)d_in[17];
    const float* Wc3 = (const float*)d_in[18]; const float* bc3 = (const float*)d_in[19];
    float* out = (float*)d_out;

    const int N = in_sizes[0] / 128;     // 100000
    const int E = in_sizes[1] / 2;       // 3200000
    const int* src = ei;
    const int* dst = ei + E;
    const int Ecap = E + 8 * N;          // padded-CSR capacity
    const int Npad = ((N + 63) / 64) * 64;
    const int NT   = (N + 63) / 64;      // 1563 row tiles
    const int NT16 = Npad / 16;          // 6252 16-row tiles

    // workspace layout (h3 first; h region doubles as hpr8B + bucket alias)
    size_t off = 0;
    auto take = [&](size_t bytes) { size_t o = off; off = WS_ALIGN(off + bytes); return o; };
    char* ws = (char*)d_ws;
    unsigned short* h3     = (unsigned short*)(ws + take((size_t)N * 64 * 2));       // 12.8MB
    unsigned short* h      = (unsigned short*)(ws + take((size_t)N * 128 * 2));      // 25.6MB
    unsigned char*  hpr8   = (unsigned char*) (ws + take((size_t)(Npad + 64) * 128));// 12.8MB
    int*            col    = (int*)(ws + take((size_t)Ecap * 4));                    // 16MB
    unsigned short* wt     = (unsigned short*)(ws + take(73728 * 2));
    float* dinv   = (float*)(ws + take((size_t)(N + 64) * 4));
    int*   cnt    = (int*)  (ws + take((size_t)N * 4));
    int*   rowptr = (int*)  (ws + take((size_t)(N + 1) * 4));
    int*   bcnt   = (int*)  (ws + take((size_t)RNG * NB * 4));
    int*   base   = (int*)  (ws + take((size_t)RNG * NB * 4));
    int*   rtot   = (int*)  (ws + take(RNG * 4));
    int*   bstart = (int*)  (ws + take((RNG + 1) * 4));
    int*   bsum   = (int*)  (ws + take(512 * 4));
    int*   boff   = (int*)  (ws + take(512 * 4));
    // aliases: bucket (12.8MB) on h [dead in CSR phase];
    // hist (6.4MB) on h3 [h3 written only by agg64, after fill2];
    // hpr8B (12.8MB fp8 double-buffer for fused agg+gemm) on h [h unused now].
    unsigned* bucket = (unsigned*)h;
    int* hist = (int*)h3;
    unsigned char* hpr8B = (unsigned char*)h;
    (void)ws_size; (void)n_in; (void)out_size;

    const int nb  = (N + 255) / 256;     // 391 (<512)
    const int gN  = (N + 255) / 256;
    const int GG  = 512;                 // gemm/head grid

    prep_w_k<<<288, 256, 0, stream>>>(W1, W2, W3, Wa1, Wc1, Wa2, Wc2, wt);
    const unsigned short* W1t  = wt;
    const unsigned short* W2t  = wt + 16384;
    const unsigned short* W3t  = wt + 32768;
    const unsigned short* Wh1t = wt + 40960;   // [256][64] concat actor|critic L1
    const unsigned short* Wa2t = wt + 57344;
    const unsigned short* Wc2t = wt + 65536;

    // CSR build
    bucket_count_k<<<NB, 256, 0, stream>>>(dst, bcnt, E);
    rsum_k<<<RNG, 256, 0, stream>>>(bcnt, base, rtot);
    rstart_k<<<1, 64, 0, stream>>>(rtot, bstart, E);
    bucket_scatter_k<<<NB, 256, 0, stream>>>(src, dst, base, bstart, bucket, E);
    hist_bucket_k<<<RNG * CHK, 256, 0, stream>>>(bucket, bstart, hist);
    sum_hist_dinv_k<<<gN, 256, 0, stream>>>(hist, cnt, dinv, N);
    chunk_sum_k<<<nb, 256, 0, stream>>>(cnt, bsum, N);
    scan_mid_k<<<1, 512, 0, stream>>>(bsum, boff, nb, rowptr, N);
    scan_off_pad_k<<<nb, 256, 0, stream>>>(cnt, boff, rowptr, hist, col, N);
    fill2_k<<<RNG * CHK, 256, 0, stream>>>(bucket, bstart, hist, col);

    // GCN layer 1: x @ W1 -> fp8 (pre-scaled by dinv)
    gemm2_k<128, 128, 0, true><<<GG, 256, 0, stream>>>(
        x, 128, W1t, dinv, nullptr, nullptr, hpr8, N, NT);
    // fused: agg(+b1,relu) @ W2 -> fp8   (hpr8 -> hpr8B)
    agg_gemm_k<128><<<2048, 256, 0, stream>>>(
        hpr8, rowptr, col, dinv, b1, W2t, hpr8B, N, Ecap, NT16);
    // fused: agg(+b2,relu) @ W3 -> fp8   (hpr8B -> hpr8, 64-ch)
    agg_gemm_k<64><<<2048, 256, 0, stream>>>(
        hpr8B, rowptr, col, dinv, b2, W3t, hpr8, N, Ecap, NT16);
    // final aggregation -> h3 bf16
    agg64_k<<<(N + 3) / 4, 256, 0, stream>>>(hpr8, rowptr, col, dinv, b3, h3, N, Ecap);

    // fused heads (h3 -> out), actor then critic
    heads_k<2><<<GG, 256, 0, stream>>>(h3, Wh1t, ba1, Wa2t, ba2, Wa3, ba3, out, N, NT);
    heads_k<3><<<GG, 256, 0, stream>>>(h3, Wh1t + 128 * 64, bc1, Wc2t, bc2, Wc3, bc3, out, N, NT);
}

// Round 3
// 482.739 us; speedup vs baseline: 1.2763x; 1.2763x over previous
//
#include <hip/hip_runtime.h>
#include <hip/hip_bf16.h>
#include <math.h>

// ---------------------------------------------------------------------------
// FederatedPPOAgent: 3x GCNConv (N=100k, E=3.2M, D=128) + actor/critic MLPs.
//
// R12 changes vs R11:
//  - agg_gemm_k REMOVED. R10/R11 post-mortem: fusing agg+GEMM made each wave
//    serially process 16 nodes (single-shot, occupancy 33%, 1.9 TB/s gather)
//    vs agg128's one-node-per-wave structure (75% occupancy, 2.85 TB/s).
//    Latency/MLP-bound, not traffic-bound: fixing the spill (R11) moved dur
//    only 182->174us. Reverted to R9's agg128_k + gemm2_k (67us + ~20us each).
//  - heads_k<2/3> KEPT (R10's win, ~-50..90us vs R9's 3-GEMM head complex):
//    weights staged once/block, per-wave 16 rows end-to-end through LDS,
//    no A1C1 51MB round-trip.
// ---------------------------------------------------------------------------

#define WS_ALIGN(x) (((x) + 255) & ~(size_t)255)

constexpr int RNG  = 64;        // node ranges
constexpr int NRG  = 1563;      // nodes per range (64*1563 >= 100000)
constexpr int NB   = 1024;      // bucket-phase blocks
constexpr int CHK  = 16;        // per-range fill chunks

constexpr float S_FP8     = 64.0f;
constexpr float S_FP8_INV = 1.0f / 64.0f;

using bf16x8 = __attribute__((ext_vector_type(8))) short;
using f32x4  = __attribute__((ext_vector_type(4))) float;
using f32x2  = __attribute__((ext_vector_type(2))) float;

__device__ __forceinline__ float b2f(unsigned short u) {
    return __uint_as_float(((unsigned int)u) << 16);
}
__device__ __forceinline__ unsigned short f2b(float f) {
    __hip_bfloat16 hb = __float2bfloat16(f);
    return *(unsigned short*)&hb;
}
__device__ __forceinline__ unsigned char f2fp8(float f) {
    return (unsigned char)(__builtin_amdgcn_cvt_pk_fp8_f32(f, f, 0, false) & 0xff);
}
__device__ __forceinline__ int pad8(int v) { return (v + 7) & ~7; }

// 8 fp8 (uint2) -> 4 packed-f32 accumulators
__device__ __forceinline__ void acc8(uint2 u, f32x2& a01, f32x2& a23,
                                     f32x2& a45, f32x2& a67) {
    a01 += __builtin_amdgcn_cvt_pk_f32_fp8((int)u.x, false);
    a23 += __builtin_amdgcn_cvt_pk_f32_fp8((int)u.x, true);
    a45 += __builtin_amdgcn_cvt_pk_f32_fp8((int)u.y, false);
    a67 += __builtin_amdgcn_cvt_pk_f32_fp8((int)u.y, true);
}

// ---------------- CSR build ----------------

__global__ __launch_bounds__(256) void bucket_count_k(
    const int* __restrict__ dst, int* __restrict__ bcnt, int E) {
    __shared__ int c64[RNG];
    int b = blockIdx.x, t = threadIdx.x;
    if (t < RNG) c64[t] = 0;
    __syncthreads();
    int ec = (E + NB - 1) / NB;
    int e0 = b * ec, e1 = min(E, e0 + ec);
    for (int e = e0 + t; e < e1; e += 256) {
        int d = __builtin_nontemporal_load(dst + e);
        atomicAdd(&c64[d / NRG], 1);
    }
    __syncthreads();
    if (t < RNG) bcnt[t * NB + b] = c64[t];
}

// block r: exclusive scan of bcnt[r][0..NB) -> base, total -> rtot[r]
__global__ __launch_bounds__(256) void rsum_k(
    const int* __restrict__ bcnt, int* __restrict__ base, int* __restrict__ rtot) {
    __shared__ int s[256];
    int r = blockIdx.x, t = threadIdx.x;
    const int* row = bcnt + (size_t)r * NB;
    int v[4], loc = 0;
#pragma unroll
    for (int j = 0; j < 4; j++) { v[j] = row[t * 4 + j]; loc += v[j]; }
    s[t] = loc;
    __syncthreads();
    for (int d = 1; d < 256; d <<= 1) {
        int x = (t >= d) ? s[t - d] : 0;
        __syncthreads();
        s[t] += x;
        __syncthreads();
    }
    int run = s[t] - loc;   // exclusive
    int* bp = base + (size_t)r * NB + t * 4;
#pragma unroll
    for (int j = 0; j < 4; j++) { bp[j] = run; run += v[j]; }
    if (t == 255) rtot[r] = s[255];
}

__global__ void rstart_k(const int* __restrict__ rtot, int* __restrict__ bstart, int E) {
    if (threadIdx.x == 0) {
        int run = 0;
        for (int r = 0; r < RNG; r++) { bstart[r] = run; run += rtot[r]; }
        bstart[RNG] = run;
    }
}

__global__ __launch_bounds__(256) void bucket_scatter_k(
    const int* __restrict__ src, const int* __restrict__ dst,
    const int* __restrict__ base, const int* __restrict__ bstart,
    unsigned* __restrict__ bucket, int E) {
    __shared__ int cur[RNG];
    int b = blockIdx.x, t = threadIdx.x;
    if (t < RNG) cur[t] = bstart[t] + base[(size_t)t * NB + b];
    __syncthreads();
    int ec = (E + NB - 1) / NB;
    int e0 = b * ec, e1 = min(E, e0 + ec);
    for (int e = e0 + t; e < e1; e += 256) {
        int d = __builtin_nontemporal_load(dst + e);
        int sv = __builtin_nontemporal_load(src + e);
        int r = d / NRG;
        int pos = atomicAdd(&cur[r], 1);
        bucket[pos] = ((unsigned)(d - r * NRG) << 17) | (unsigned)sv;
    }
}

__global__ __launch_bounds__(256) void hist_bucket_k(
    const unsigned* __restrict__ bucket, const int* __restrict__ bstart,
    int* __restrict__ hist) {
    __shared__ int h[NRG];
    int b = blockIdx.x, r = b & 63, c2 = b >> 6, t = threadIdx.x;
    for (int i = t; i < NRG; i += 256) h[i] = 0;
    int s0 = bstart[r], s1 = bstart[r + 1];
    int ec = (s1 - s0 + CHK - 1) / CHK;
    int e0 = s0 + c2 * ec, e1 = min(s1, e0 + ec);
    __syncthreads();
    for (int e = e0 + t; e < e1; e += 256) {
        unsigned v = __builtin_nontemporal_load(bucket + e);
        atomicAdd(&h[v >> 17], 1);
    }
    __syncthreads();
    int* out = hist + ((size_t)r * CHK + c2) * NRG;
    for (int i = t; i < NRG; i += 256) out[i] = h[i];
}

__global__ void sum_hist_dinv_k(const int* __restrict__ hist, int* __restrict__ cnt,
                                float* __restrict__ dinv, int N) {
    int i = blockIdx.x * 256 + threadIdx.x;
    if (i >= N) return;
    int r = i / NRG, li = i - r * NRG;
    const int* hp = hist + ((size_t)r * CHK) * NRG + li;
    int s = 0;
#pragma unroll
    for (int c = 0; c < CHK; c++) s += hp[(size_t)c * NRG];
    cnt[i] = s;
    dinv[i] = rsqrtf((float)s + 1.0f);   // +1: self loop
}

// prefix sums over PADDED counts (pad8)
__global__ void chunk_sum_k(const int* __restrict__ cnt, int* __restrict__ bsum, int n) {
    __shared__ int sd[256];
    int t = threadIdx.x;
    int i = blockIdx.x * 256 + t;
    sd[t] = (i < n) ? pad8(cnt[i]) : 0;
    __syncthreads();
    for (int d = 128; d > 0; d >>= 1) {
        if (t < d) sd[t] += sd[t + d];
        __syncthreads();
    }
    if (t == 0) bsum[blockIdx.x] = sd[0];
}

__global__ void scan_mid_k(const int* __restrict__ bsum, int* __restrict__ boff,
                           int nb, int* __restrict__ rowptr, int N) {
    __shared__ int s[512];
    int t = threadIdx.x;
    s[t] = (t < nb) ? bsum[t] : 0;
    __syncthreads();
    if (t == 0) {
        int run = 0;
        for (int i = 0; i < nb; i++) { int v = s[i]; s[i] = run; run += v; }
        rowptr[N] = run;
    }
    __syncthreads();
    if (t < nb) boff[t] = s[t];
}

// scan_final + offsets + pad_col fused
__global__ void scan_off_pad_k(const int* __restrict__ cnt, const int* __restrict__ boff,
                               int* __restrict__ rowptr, int* __restrict__ hist,
                               int* __restrict__ col, int N) {
    __shared__ int s[256];
    int t = threadIdx.x;
    int i = blockIdx.x * 256 + t;
    int cv = (i < N) ? cnt[i] : 0;
    int v = pad8(cv);
    if (i >= N) v = 0;
    s[t] = v;
    __syncthreads();
    for (int d = 1; d < 256; d <<= 1) {
        int x = (t >= d) ? s[t - d] : 0;
        __syncthreads();
        s[t] += x;
        __syncthreads();
    }
    if (i < N) {
        int rp = s[t] - v + boff[blockIdx.x];
        rowptr[i] = rp;
        // offsets: hist[r][c][li] -> running cursor
        int r = i / NRG, li = i - r * NRG;
        int* hp = hist + ((size_t)r * CHK) * NRG + li;
        int run = rp;
#pragma unroll
        for (int c = 0; c < CHK; c++) {
            int hv = hp[(size_t)c * NRG];
            hp[(size_t)c * NRG] = run;
            run += hv;
        }
        // pad slots -> zero-row N
        for (int e = rp + cv; e < rp + v; e++) col[e] = N;
    }
}

__global__ __launch_bounds__(256) void fill2_k(
    const unsigned* __restrict__ bucket, const int* __restrict__ bstart,
    const int* __restrict__ hist, int* __restrict__ col) {
    __shared__ int cur[NRG];
    int b = blockIdx.x, r = b & 63, c2 = b >> 6, t = threadIdx.x;
    const int* hp = hist + ((size_t)r * CHK + c2) * NRG;
    for (int i = t; i < NRG; i += 256) cur[i] = hp[i];
    int s0 = bstart[r], s1 = bstart[r + 1];
    int ec = (s1 - s0 + CHK - 1) / CHK;
    int e0 = s0 + c2 * ec, e1 = min(s1, e0 + ec);
    __syncthreads();
    for (int e = e0 + t; e < e1; e += 256) {
        unsigned v = __builtin_nontemporal_load(bucket + e);
        int slot = atomicAdd(&cur[v >> 17], 1);   // LDS atomic
        col[slot] = (int)(v & 0x1FFFFu);
    }
}

// ---------------- weight prep: fp32 W[K][OUT] -> bf16 W^T[OUT][K] ----------------
// Layout: W1t(16384) W2t(16384) W3t(8192) Wh1t(16384: Wa1 rows 0..127,
// Wc1 rows 128..255, K=64) Wa2t(8192) Wc2t(8192)

__global__ __launch_bounds__(256) void prep_w_k(
    const float* __restrict__ W1, const float* __restrict__ W2,
    const float* __restrict__ W3, const float* __restrict__ Wa1,
    const float* __restrict__ Wc1, const float* __restrict__ Wa2,
    const float* __restrict__ Wc2, unsigned short* __restrict__ wt) {
    int i = blockIdx.x * 256 + threadIdx.x;   // 0..73727
    const float* W; int off, K, OUT;
    if (i < 16384)      { W = W1;  off = 0;     K = 128; OUT = 128; }
    else if (i < 32768) { W = W2;  off = 16384; K = 128; OUT = 128; }
    else if (i < 40960) { W = W3;  off = 32768; K = 128; OUT = 64; }
    else if (i < 49152) { W = Wa1; off = 40960; K = 64;  OUT = 128; }
    else if (i < 57344) { W = Wc1; off = 49152; K = 64;  OUT = 128; }
    else if (i < 65536) { W = Wa2; off = 57344; K = 128; OUT = 64; }
    else                { W = Wc2; off = 65536; K = 128; OUT = 64; }
    int j = i - off, k = j / OUT, n = j - k * OUT;
    wt[off + n * K + k] = f2b(W[j]);
}

// ---------------- gemm2: weights-stationary grid-stride MFMA GEMM ----------------
// EPI 0: fp8(acc * dinv[row] * S), unguarded rows (zero pad-row at N)

template <int K, int OUT, int EPI, bool AF32>
__global__ __launch_bounds__(256) void gemm2_k(
    const void* __restrict__ Xv, int ldx, const unsigned short* __restrict__ Wt,
    const float* __restrict__ sb, const float* __restrict__ w3b,
    const float* __restrict__ b3, void* __restrict__ Yv, int N, int NT) {
    constexpr int LDK = K + 8;
    __shared__ __align__(16) unsigned short Bs[OUT * LDK];
    __shared__ __align__(16) unsigned short As[64 * LDK];
    int t = threadIdx.x;

    // stage B once per block (visible after first in-loop barrier)
    for (int g = t; g < OUT * (K / 8); g += 256) {
        int r = g / (K / 8), q = g - r * (K / 8);
        *(uint4*)&Bs[r * LDK + q * 8] = *(const uint4*)(Wt + r * K + q * 8);
    }

    int wv = t >> 6, lane = t & 63;
    int lm = lane & 15, lq = lane >> 4;
    constexpr int CT = OUT / 16;

    for (int tile = blockIdx.x; tile < NT; tile += gridDim.x) {
        int rowBase = tile * 64;

        // stage A tile
        if constexpr (AF32) {
            const float* X = (const float*)Xv;
            for (int g = t; g < 64 * (K / 8); g += 256) {
                int r = g / (K / 8), q = g - r * (K / 8);
                int gr = rowBase + r;
                unsigned short us[8];
                if (gr < N) {
                    float4 v0 = *(const float4*)(X + (size_t)gr * ldx + q * 8);
                    float4 v1 = *(const float4*)(X + (size_t)gr * ldx + q * 8 + 4);
                    us[0] = f2b(v0.x); us[1] = f2b(v0.y); us[2] = f2b(v0.z); us[3] = f2b(v0.w);
                    us[4] = f2b(v1.x); us[5] = f2b(v1.y); us[6] = f2b(v1.z); us[7] = f2b(v1.w);
                } else {
#pragma unroll
                    for (int j = 0; j < 8; j++) us[j] = 0;
                }
                *(uint4*)&As[r * LDK + q * 8] = *(uint4*)us;
            }
        } else {
            const unsigned short* X = (const unsigned short*)Xv;
            for (int g = t; g < 64 * (K / 8); g += 256) {
                int r = g / (K / 8), q = g - r * (K / 8);
                int gr = rowBase + r;
                uint4 v = make_uint4(0, 0, 0, 0);
                if (gr < N) v = *(const uint4*)(X + (size_t)gr * ldx + q * 8);
                *(uint4*)&As[r * LDK + q * 8] = v;
            }
        }
        __syncthreads();

        f32x4 acc[CT];
#pragma unroll
        for (int c = 0; c < CT; c++) acc[c] = (f32x4){0.f, 0.f, 0.f, 0.f};

        const unsigned short* arow = &As[(wv * 16 + lm) * LDK + lq * 8];
#pragma unroll
        for (int kt = 0; kt < K / 32; kt++) {
            bf16x8 a = *(const bf16x8*)(arow + kt * 32);
#pragma unroll
            for (int c = 0; c < CT; c++) {
                bf16x8 b = *(const bf16x8*)&Bs[(c * 16 + lm) * LDK + kt * 32 + lq * 8];
                acc[c] = __builtin_amdgcn_mfma_f32_16x16x32_bf16(a, b, acc[c], 0, 0, 0);
            }
        }

        // epilogue: C/D layout col=lane&15, row=(lane>>4)*4+reg [m89/m91]
        int r0 = rowBase + wv * 16 + lq * 4;
        if constexpr (EPI == 0) {
#pragma unroll
            for (int r = 0; r < 4; r++) {
                int gr = r0 + r;
                float scale = (gr < N) ? sb[gr] * S_FP8 : 0.f;
#pragma unroll
                for (int c = 0; c < CT; c++) {
                    int colg = c * 16 + lm;
                    ((unsigned char*)Yv)[(size_t)gr * OUT + colg] = f2fp8(acc[c][r] * scale);
                }
            }
        }
        __syncthreads();   // protect As before next tile's staging
    }
}

// ---------------- aggregation (one node per wave; R9-proven) ----------------

template <bool RELU>
__global__ __launch_bounds__(256) void agg128_k(
    const unsigned char* __restrict__ H,   // [(Npad+64),128] fp8, rows>=N zero
    const int* __restrict__ rowptr, const int* __restrict__ col,
    const float* __restrict__ dinv, const float* __restrict__ bias,
    unsigned short* __restrict__ Y, int N, int Ecap) {
    int tid = threadIdx.x;
    int node = blockIdx.x * 4 + (tid >> 6);
    if (node >= N) return;
    int lane = tid & 63;
    int grp = lane >> 4;
    int li8 = (lane & 15) * 8;

    f32x2 a01 = {0.f, 0.f}, a23 = {0.f, 0.f}, a45 = {0.f, 0.f}, a67 = {0.f, 0.f};
    if (grp == 0) {
        uint2 u = *(const uint2*)(H + (size_t)node * 128 + li8);
        acc8(u, a01, a23, a45, a67);
    }

    int start = rowptr[node], end = rowptr[node + 1];
    for (int e0 = start; e0 < end; e0 += 64) {
        int cv = col[min(e0 + lane, Ecap - 1)];
        int quads = min(64, end - e0) >> 2;
        for (int q = 0; q < quads; q += 2) {
            int s0 = __shfl(cv, 4 * q + grp, 64);
            int s1 = __shfl(cv, 4 * q + 4 + grp, 64);
            uint2 u0 = *(const uint2*)(H + (size_t)s0 * 128 + li8);
            uint2 u1 = *(const uint2*)(H + (size_t)s1 * 128 + li8);
            acc8(u0, a01, a23, a45, a67);
            acc8(u1, a01, a23, a45, a67);
        }
    }

#pragma unroll
    for (int w = 16; w < 64; w <<= 1) {
        a01[0] += __shfl_xor(a01[0], w, 64); a01[1] += __shfl_xor(a01[1], w, 64);
        a23[0] += __shfl_xor(a23[0], w, 64); a23[1] += __shfl_xor(a23[1], w, 64);
        a45[0] += __shfl_xor(a45[0], w, 64); a45[1] += __shfl_xor(a45[1], w, 64);
        a67[0] += __shfl_xor(a67[0], w, 64); a67[1] += __shfl_xor(a67[1], w, 64);
    }

    if (grp == 0) {
        float dv = dinv[node] * S_FP8_INV;
        float4 b0 = *(const float4*)(bias + li8);
        float4 b1 = *(const float4*)(bias + li8 + 4);
        float o0 = a01[0] * dv + b0.x, o1 = a01[1] * dv + b0.y;
        float o2 = a23[0] * dv + b0.z, o3 = a23[1] * dv + b0.w;
        float o4 = a45[0] * dv + b1.x, o5 = a45[1] * dv + b1.y;
        float o6 = a67[0] * dv + b1.z, o7 = a67[1] * dv + b1.w;
        if (RELU) {
            o0 = fmaxf(o0, 0.f); o1 = fmaxf(o1, 0.f); o2 = fmaxf(o2, 0.f); o3 = fmaxf(o3, 0.f);
            o4 = fmaxf(o4, 0.f); o5 = fmaxf(o5, 0.f); o6 = fmaxf(o6, 0.f); o7 = fmaxf(o7, 0.f);
        }
        unsigned short us[8] = {f2b(o0), f2b(o1), f2b(o2), f2b(o3),
                                f2b(o4), f2b(o5), f2b(o6), f2b(o7)};
        *(uint4*)(Y + (size_t)node * 128 + li8) = *(uint4*)us;
    }
}

__global__ __launch_bounds__(256) void agg64_k(
    const unsigned char* __restrict__ H,   // [(Npad+64),64] fp8, rows>=N zero
    const int* __restrict__ rowptr, const int* __restrict__ col,
    const float* __restrict__ dinv, const float* __restrict__ bias,
    unsigned short* __restrict__ Y, int N, int Ecap) {
    int tid = threadIdx.x;
    int node = blockIdx.x * 4 + (tid >> 6);
    if (node >= N) return;
    int lane = tid & 63;
    int grp = lane >> 3;
    int li8 = (lane & 7) * 8;

    f32x2 a01 = {0.f, 0.f}, a23 = {0.f, 0.f}, a45 = {0.f, 0.f}, a67 = {0.f, 0.f};
    if (grp == 0) {
        uint2 u = *(const uint2*)(H + (size_t)node * 64 + li8);
        acc8(u, a01, a23, a45, a67);
    }

    int start = rowptr[node], end = rowptr[node + 1];
    for (int e0 = start; e0 < end; e0 += 64) {
        int cv = col[min(e0 + lane, Ecap - 1)];
        int octs = min(64, end - e0) >> 3;
        int o = 0;
        for (; o + 2 <= octs; o += 2) {
            int s0 = __shfl(cv, 8 * o + grp, 64);
            int s1 = __shfl(cv, 8 * o + 8 + grp, 64);
            uint2 u0 = *(const uint2*)(H + (size_t)s0 * 64 + li8);
            uint2 u1 = *(const uint2*)(H + (size_t)s1 * 64 + li8);
            acc8(u0, a01, a23, a45, a67);
            acc8(u1, a01, a23, a45, a67);
        }
        if (o < octs) {
            int s0 = __shfl(cv, 8 * o + grp, 64);
            uint2 u0 = *(const uint2*)(H + (size_t)s0 * 64 + li8);
            acc8(u0, a01, a23, a45, a67);
        }
    }

#pragma unroll
    for (int w = 8; w < 64; w <<= 1) {
        a01[0] += __shfl_xor(a01[0], w, 64); a01[1] += __shfl_xor(a01[1], w, 64);
        a23[0] += __shfl_xor(a23[0], w, 64); a23[1] += __shfl_xor(a23[1], w, 64);
        a45[0] += __shfl_xor(a45[0], w, 64); a45[1] += __shfl_xor(a45[1], w, 64);
        a67[0] += __shfl_xor(a67[0], w, 64); a67[1] += __shfl_xor(a67[1], w, 64);
    }

    if (grp == 0) {
        float dv = dinv[node] * S_FP8_INV;
        float4 b0 = *(const float4*)(bias + li8);
        float4 b1 = *(const float4*)(bias + li8 + 4);
        unsigned short us[8] = {
            f2b(a01[0] * dv + b0.x), f2b(a01[1] * dv + b0.y),
            f2b(a23[0] * dv + b0.z), f2b(a23[1] * dv + b0.w),
            f2b(a45[0] * dv + b1.x), f2b(a45[1] * dv + b1.y),
            f2b(a67[0] * dv + b1.z), f2b(a67[1] * dv + b1.w)};
        *(uint4*)(Y + (size_t)node * 64 + li8) = *(uint4*)us;
    }
}

// ---------------- fused actor/critic heads ----------------
// EPI 2: actor  (L1 relu -> L2 relu -> logits -> softmax -> out[0..8))
// EPI 3: critic (L1 relu -> L2 relu -> value -> out[8])
// Weights staged once per block; per 64-row tile each wave handles its own
// 16 rows end-to-end through wave-private LDS (no per-tile barriers).

template <int EPI>
__global__ __launch_bounds__(256) void heads_k(
    const unsigned short* __restrict__ h3,   // [N,64] bf16
    const unsigned short* __restrict__ W1t,  // [128][64] bf16 (head L1)
    const float* __restrict__ b1v,           // [128]
    const unsigned short* __restrict__ W2t,  // [64][128] bf16 (head L2)
    const float* __restrict__ b2v,           // [64]
    const float* __restrict__ w3,            // Wa3 [64][8] / Wc3 [64][1] fp32
    const float* __restrict__ b3v,
    float* __restrict__ out, int N, int NT) {
    constexpr int LD64 = 72, LD128 = 136;
    __shared__ __align__(16) unsigned short Bs1[128 * LD64];   // 18.4KB
    __shared__ __align__(16) unsigned short Bs2[64 * LD128];   // 17.4KB
    __shared__ __align__(16) unsigned short As[4 * 16 * LD64]; //  9.2KB
    __shared__ __align__(16) unsigned short A1[4 * 16 * LD128];// 17.4KB
    int t = threadIdx.x, wv = t >> 6, lane = t & 63;
    int lm = lane & 15, lq = lane >> 4;

    // stage head weights once per block
    for (int g = t; g < 128 * 8; g += 256) {
        int r = g >> 3, q = g & 7;
        *(uint4*)&Bs1[r * LD64 + q * 8] = *(const uint4*)(W1t + r * 64 + q * 8);
    }
    for (int g = t; g < 64 * 16; g += 256) {
        int r = g >> 4, q = g & 15;
        *(uint4*)&Bs2[r * LD128 + q * 8] = *(const uint4*)(W2t + r * 128 + q * 8);
    }
    __syncthreads();

    unsigned short* Asw = &As[wv * 16 * LD64];
    unsigned short* A1w = &A1[wv * 16 * LD128];

    for (int tile = blockIdx.x; tile < NT; tile += gridDim.x) {
        int rowBase = tile * 64 + wv * 16;

        // stage wave's 16 h3 rows
        for (int g = lane; g < 16 * 8; g += 64) {
            int r = g >> 3, q = g & 7;
            int gr = rowBase + r;
            uint4 v = make_uint4(0, 0, 0, 0);
            if (gr < N) v = *(const uint4*)(h3 + (size_t)gr * 64 + q * 8);
            *(uint4*)&Asw[r * LD64 + q * 8] = v;
        }

        // L1: 16x128, K=64
        f32x4 acc1[8];
#pragma unroll
        for (int c = 0; c < 8; c++) acc1[c] = (f32x4){0.f, 0.f, 0.f, 0.f};
        const unsigned short* arow = &Asw[lm * LD64 + lq * 8];
#pragma unroll
        for (int kt = 0; kt < 2; kt++) {
            bf16x8 a = *(const bf16x8*)(arow + kt * 32);
#pragma unroll
            for (int c = 0; c < 8; c++) {
                bf16x8 b = *(const bf16x8*)&Bs1[(c * 16 + lm) * LD64 + kt * 32 + lq * 8];
                acc1[c] = __builtin_amdgcn_mfma_f32_16x16x32_bf16(a, b, acc1[c], 0, 0, 0);
            }
        }
        // relu + bf16 -> wave-private A1
#pragma unroll
        for (int r = 0; r < 4; r++) {
            int lr = lq * 4 + r;
#pragma unroll
            for (int c = 0; c < 8; c++) {
                int colg = c * 16 + lm;
                float v = fmaxf(acc1[c][r] + b1v[colg], 0.f);
                A1w[lr * LD128 + colg] = f2b(v);
            }
        }

        // L2: 16x64, K=128
        f32x4 acc[4];
#pragma unroll
        for (int c = 0; c < 4; c++) acc[c] = (f32x4){0.f, 0.f, 0.f, 0.f};
        const unsigned short* arow2 = &A1w[lm * LD128 + lq * 8];
#pragma unroll
        for (int kt = 0; kt < 4; kt++) {
            bf16x8 a = *(const bf16x8*)(arow2 + kt * 32);
#pragma unroll
            for (int c = 0; c < 4; c++) {
                bf16x8 b = *(const bf16x8*)&Bs2[(c * 16 + lm) * LD128 + kt * 32 + lq * 8];
                acc[c] = __builtin_amdgcn_mfma_f32_16x16x32_bf16(a, b, acc[c], 0, 0, 0);
            }
        }

        int r0 = rowBase + lq * 4;
        if constexpr (EPI == 2) {
            float l[4][8];
#pragma unroll
            for (int r = 0; r < 4; r++)
#pragma unroll
                for (int a = 0; a < 8; a++) l[r][a] = 0.f;
#pragma unroll
            for (int c = 0; c < 4; c++) {
                int colg = c * 16 + lm;
#pragma unroll
                for (int r = 0; r < 4; r++) {
                    float v = fmaxf(acc[c][r] + b2v[colg], 0.f);
#pragma unroll
                    for (int a = 0; a < 8; a++)
                        l[r][a] = fmaf(v, w3[colg * 8 + a], l[r][a]);
                }
            }
#pragma unroll
            for (int w = 1; w < 16; w <<= 1)
#pragma unroll
                for (int r = 0; r < 4; r++)
#pragma unroll
                    for (int a = 0; a < 8; a++)
                        l[r][a] += __shfl_xor(l[r][a], w, 64);
            if (lm < 8) {
#pragma unroll
                for (int r = 0; r < 4; r++) {
                    int gr = r0 + r;
                    if (gr < N) {
                        float lg[8], m = -1e30f;
#pragma unroll
                        for (int a = 0; a < 8; a++) { lg[a] = l[r][a] + b3v[a]; m = fmaxf(m, lg[a]); }
                        float sum = 0.f;
#pragma unroll
                        for (int a = 0; a < 8; a++) { lg[a] = expf(lg[a] - m); sum += lg[a]; }
                        out[(size_t)gr * 9 + lm] = lg[lm] / sum;
                    }
                }
            }
        } else {   // EPI == 3: critic value
            float lv[4] = {0.f, 0.f, 0.f, 0.f};
#pragma unroll
            for (int c = 0; c < 4; c++) {
                int colg = c * 16 + lm;
#pragma unroll
                for (int r = 0; r < 4; r++) {
                    float v = fmaxf(acc[c][r] + b2v[colg], 0.f);
                    lv[r] = fmaf(v, w3[colg], lv[r]);
                }
            }
#pragma unroll
            for (int w = 1; w < 16; w <<= 1)
#pragma unroll
                for (int r = 0; r < 4; r++) lv[r] += __shfl_xor(lv[r], w, 64);
            if (lm == 0) {
#pragma unroll
                for (int r = 0; r < 4; r++) {
                    int gr = r0 + r;
                    if (gr < N) out[(size_t)gr * 9 + 8] = lv[r] + b3v[0];
                }
            }
        }
    }
}

// ---------------- launch ----------------

extern "C" void kernel_launch(void* const* d_in, const int* in_sizes, int n_in,
                              void* d_out, int out_size, void* d_ws, size_t ws_size,
                              hipStream_t stream) {
    const float* x   = (const float*)d_in[0];
    const int*   ei  = (const int*)d_in[1];
    const float* W1  = (const float*)d_in[2];  const float* b1  = (const float*)d_in[3];
    const float* W2  = (const float*)d_in[4];  const float* b2  = (const float*)d_in[5];
    const float* W3  = (const float*)d_in[6];  const float* b3  = (const float*)d_in[7];
    const float* Wa1 = (const float*)d_in[8];  const float* ba1 = (const float*)d_in[9];
    const float* Wa2 = (const float*)d_in[10]; const float* ba2 = (const float*)d_in[11];
    const float* Wa3 = (const float*)d_in[12]; const float* ba3 = (const float*)d_in[13];
    const float* Wc1 = (const float*)d_in[14]; const float* bc1 = (const float*)d_in[15];
    const float* Wc2 = (const float*)d_in[16]; const float* bc2 = (const float*)d_in[17];
    const float* Wc3 = (const float*)d_in[18]; const float* bc3 = (const float*)d_in[19];
    float* out = (float*)d_out;

    const int N = in_sizes[0] / 128;     // 100000
    const int E = in_sizes[1] / 2;       // 3200000
    const int* src = ei;
    const int* dst = ei + E;
    const int Ecap = E + 8 * N;          // padded-CSR capacity
    const int Npad = ((N + 63) / 64) * 64;
    const int NT   = (N + 63) / 64;      // 1563 row tiles

    // workspace layout
    size_t off = 0;
    auto take = [&](size_t bytes) { size_t o = off; off = WS_ALIGN(off + bytes); return o; };
    char* ws = (char*)d_ws;
    unsigned short* h3     = (unsigned short*)(ws + take((size_t)N * 64 * 2));       // 12.8MB
    unsigned short* h      = (unsigned short*)(ws + take((size_t)N * 128 * 2));      // 25.6MB
    unsigned char*  hpr8   = (unsigned char*) (ws + take((size_t)(Npad + 64) * 128));// 12.8MB
    int*            col    = (int*)(ws + take((size_t)Ecap * 4));                    // 16MB
    unsigned short* wt     = (unsigned short*)(ws + take(73728 * 2));
    float* dinv   = (float*)(ws + take((size_t)(N + 64) * 4));
    int*   cnt    = (int*)  (ws + take((size_t)N * 4));
    int*   rowptr = (int*)  (ws + take((size_t)(N + 1) * 4));
    int*   bcnt   = (int*)  (ws + take((size_t)RNG * NB * 4));
    int*   base   = (int*)  (ws + take((size_t)RNG * NB * 4));
    int*   rtot   = (int*)  (ws + take(RNG * 4));
    int*   bstart = (int*)  (ws + take((RNG + 1) * 4));
    int*   bsum   = (int*)  (ws + take(512 * 4));
    int*   boff   = (int*)  (ws + take(512 * 4));
    // aliases: bucket (12.8MB) on h [h written first by agg128, after fill2];
    // hist (6.4MB) on h3 [h3 written only by agg64, after fill2].
    unsigned* bucket = (unsigned*)h;
    int* hist = (int*)h3;
    (void)ws_size; (void)n_in; (void)out_size;

    const int nb  = (N + 255) / 256;     // 391 (<512)
    const int gN  = (N + 255) / 256;
    const int GG  = 512;                 // gemm/head grid

    prep_w_k<<<288, 256, 0, stream>>>(W1, W2, W3, Wa1, Wc1, Wa2, Wc2, wt);
    const unsigned short* W1t  = wt;
    const unsigned short* W2t  = wt + 16384;
    const unsigned short* W3t  = wt + 32768;
    const unsigned short* Wh1t = wt + 40960;   // [256][64] concat actor|critic L1
    const unsigned short* Wa2t = wt + 57344;
    const unsigned short* Wc2t = wt + 65536;

    // CSR build
    bucket_count_k<<<NB, 256, 0, stream>>>(dst, bcnt, E);
    rsum_k<<<RNG, 256, 0, stream>>>(bcnt, base, rtot);
    rstart_k<<<1, 64, 0, stream>>>(rtot, bstart, E);
    bucket_scatter_k<<<NB, 256, 0, stream>>>(src, dst, base, bstart, bucket, E);
    hist_bucket_k<<<RNG * CHK, 256, 0, stream>>>(bucket, bstart, hist);
    sum_hist_dinv_k<<<gN, 256, 0, stream>>>(hist, cnt, dinv, N);
    chunk_sum_k<<<nb, 256, 0, stream>>>(cnt, bsum, N);
    scan_mid_k<<<1, 512, 0, stream>>>(bsum, boff, nb, rowptr, N);
    scan_off_pad_k<<<nb, 256, 0, stream>>>(cnt, boff, rowptr, hist, col, N);
    fill2_k<<<RNG * CHK, 256, 0, stream>>>(bucket, bstart, hist, col);

    // GCN layer 1..3 (gemm -> fp8 -> gather-agg, R9-proven path)
    gemm2_k<128, 128, 0, true><<<GG, 256, 0, stream>>>(
        x, 128, W1t, dinv, nullptr, nullptr, hpr8, N, NT);
    agg128_k<true><<<(N + 3) / 4, 256, 0, stream>>>(hpr8, rowptr, col, dinv, b1, h, N, Ecap);
    gemm2_k<128, 128, 0, false><<<GG, 256, 0, stream>>>(
        h, 128, W2t, dinv, nullptr, nullptr, hpr8, N, NT);
    agg128_k<true><<<(N + 3) / 4, 256, 0, stream>>>(hpr8, rowptr, col, dinv, b2, h, N, Ecap);
    gemm2_k<128, 64, 0, false><<<GG, 256, 0, stream>>>(
        h, 128, W3t, dinv, nullptr, nullptr, hpr8, N, NT);
    agg64_k<<<(N + 3) / 4, 256, 0, stream>>>(hpr8, rowptr, col, dinv, b3, h3, N, Ecap);

    // fused heads (h3 -> out), actor then critic
    heads_k<2><<<GG, 256, 0, stream>>>(h3, Wh1t, ba1, Wa2t, ba2, Wa3, ba3, out, N, NT);
    heads_k<3><<<GG, 256, 0, stream>>>(h3, Wh1t + 128 * 64, bc1, Wc2t, bc2, Wc3, bc3, out, N, NT);
}